// Round 3
// baseline (387.200 us; speedup 1.0000x reference)
//
#include <hip/hip_runtime.h>
#include <cstddef>

// ---------------- problem constants ----------------
constexpr int BATCH = 4096;
constexpr int ITEM_COLS = 10242;

// Fu row offsets (fp32 fused table: user fields + rate)
constexpr int R_GENDER = 0;      // 98 rows
constexpr int R_AGE    = 98;     // 7
constexpr int R_OCC    = 105;    // 21
constexpr int R_AREA   = 126;    // 3402
constexpr int R_RATE   = 3528;   // 6
constexpr int R_FU     = 3534;   // total Fu rows; row 3534 = NEW

// padded-col space: 9 chunks concatenated, each 128-aligned.
// padded col g (chunk ch) <-> item col c = g + DLT[ch]; valid iff LOG[ch] <= g < HIG[ch].
__device__ const int CUM[10] = {0, 128, 1280, 2432, 3840, 5248, 6656, 8064, 9472, 10880};
__device__ const int DLT[9]  = {0, -104, -168, -224, -296, -368, -432, -504, -576};
__device__ const int LOG[9]  = {1, 130, 1287, 2436, 3846, 5256, 6659, 8069, 9479};
__device__ const int HIG[9]  = {26, 1223, 2380, 3774, 5184, 6595, 7997, 9407, 10818};
constexpr int FB2COLS = 10880;          // 85 tiles of 128
constexpr int NTILE   = 85;
constexpr int NSLICE  = 15;             // group-aligned K-slices
// slice s covers tiles [TS_[s], TS_[s+1]); genre={tile 0}, director=tiles 1..18, actor=19..84
__device__ const int TS_[16] = {0, 1, 7, 13, 19, 25, 31, 37, 43, 49, 55, 61, 67, 73, 79, 85};

constexpr int NFUSEA = 884;             // 884*4 >= R_FU+1 rows
constexpr int NFUSET = FB2COLS / 64;    // 170 B-table blocks
constexpr int NPACK  = 1024;            // 1024*4 waves = 4096 rows

// pack metadata: per 64-bit mask word wq: validity mask + item-col base (compile-time)
struct PackTab { unsigned long long vm[NFUSET]; int c0[NFUSET]; };
constexpr PackTab make_packtab() {
    PackTab p{};
    const int CUMc[10] = {0, 128, 1280, 2432, 3840, 5248, 6656, 8064, 9472, 10880};
    const int DLTc[9]  = {0, -104, -168, -224, -296, -368, -432, -504, -576};
    const int LOGc[9]  = {1, 130, 1287, 2436, 3846, 5256, 6659, 8069, 9479};
    const int HIGc[9]  = {26, 1223, 2380, 3774, 5184, 6595, 7997, 9407, 10818};
    for (int wq = 0; wq < NFUSET; ++wq) {
        int g0 = wq * 64;
        int ch = 0;
        while (g0 >= CUMc[ch + 1]) ++ch;
        int lo = LOGc[ch] - g0; lo = lo < 0 ? 0 : lo;                  // in [0,63]
        int hi = HIGc[ch] - g0; hi = hi < 0 ? 0 : (hi > 64 ? 64 : hi); // in [0,64]
        unsigned long long hm = (hi >= 64) ? ~0ull : ((1ull << hi) - 1ull);
        unsigned long long lm = (lo <= 0) ? 0ull : ((1ull << lo) - 1ull);
        p.vm[wq] = hm & ~lm;
        p.c0[wq] = g0 + DLTc[ch];
    }
    return p;
}
__device__ constexpr PackTab PT = make_packtab();

// workspace layout (float slots)
constexpr size_t OFF_FU  = 0;                                    // 3534*64
constexpr size_t OFF_NEW = OFF_FU + (size_t)R_FU * 64;           // 64
constexpr size_t OFF_FBT = OFF_NEW + 64;                         // B2: 64*10880 bf16
constexpr size_t OFF_MSK = OFF_FBT + (size_t)64 * FB2COLS / 2;   // 4096*170 u64
constexpr size_t OFF_X   = OFF_MSK + (size_t)BATCH * (FB2COLS / 64) * 2;
constexpr size_t OFF_Y   = OFF_X + (size_t)BATCH * 64;
constexpr size_t OFF_P   = OFF_Y + (size_t)BATCH * 64;           // NSLICE*4096*64
constexpr size_t OFF_C   = OFF_P + (size_t)NSLICE * BATCH * 64;  // NSLICE*4096
constexpr size_t OFF_SP  = OFF_C + (size_t)NSLICE * BATCH;       // 256*256
constexpr size_t OFF_SC  = OFF_SP + 256ull * 256;                // 4*4096

typedef __attribute__((ext_vector_type(8))) short bf16x8;
typedef __attribute__((ext_vector_type(4))) float f32x4;
typedef __attribute__((ext_vector_type(4))) unsigned u32x4;

__device__ __forceinline__ float lrelu(float v) { return v >= 0.0f ? v : 0.01f * v; }

__device__ __forceinline__ unsigned bf_rne_pair(float lo, float hi) {
    unsigned ul = __builtin_bit_cast(unsigned, lo);
    unsigned uh = __builtin_bit_cast(unsigned, hi);
    ul += 0x7fffu + ((ul >> 16) & 1u);
    uh += 0x7fffu + ((uh >> 16) & 1u);
    return (ul >> 16) | (uh & 0xffff0000u);
}

// ---------------- K1: fused preprocessing ----------------
// blocks [0, NFUSEA): Fu rows (4/block) + NEW row.
// blocks [NFUSEA, NFUSEA+NFUSET): B2 table, MFMA-fragment-ordered bf16, pre-masked.
// blocks [NFUSEA+NFUSET, +NPACK): bit-pack item rows -> M64 (validity-masked).
__global__ __launch_bounds__(256) void k_fuse(
        const float* __restrict__ gender_tab, const float* __restrict__ age_tab,
        const float* __restrict__ occ_tab, const float* __restrict__ area_tab,
        const float* __restrict__ user_W, const float* __restrict__ rate_tab,
        const float* __restrict__ item_W, const float* __restrict__ edges_tab,
        const float* __restrict__ edge_W, const float* __restrict__ genre_W,
        const float* __restrict__ director_W, const float* __restrict__ actor_W,
        const int* __restrict__ item,
        float* __restrict__ Fu, float* __restrict__ NEWt, short* __restrict__ B2s,
        unsigned long long* __restrict__ M64) {
    const int t = threadIdx.x;
    const int blk = blockIdx.x;

    if (blk >= NFUSEA + NFUSET) {
        // ---- pack role: one wave per batch row, coalesced 256B stream + ballot ----
        const int w = __builtin_amdgcn_readfirstlane(t >> 6);
        const int lane = t & 63;
        const int m = (blk - (NFUSEA + NFUSET)) * 4 + w;
        const int* row = item + (size_t)m * ITEM_COLS;
        unsigned long long* dst = M64 + (size_t)m * (FB2COLS / 64);
#pragma unroll 2
        for (int wq = 0; wq < FB2COLS / 64; ++wq) {
            int c = PT.c0[wq] + lane;
            c = c > (ITEM_COLS - 1) ? (ITEM_COLS - 1) : c;   // tail clamp (bits masked)
            unsigned long long b = __ballot(row[c] != 0) & PT.vm[wq];
            if (lane == 0) dst[wq] = b;
        }
        return;
    }

    const int n = t & 63;
    const int rb = __builtin_amdgcn_readfirstlane(t >> 6);
    __shared__ float T[64 * 65];

    if (blk < NFUSEA) {
        int r = blk * 4 + rb;
        if (r > R_FU) return;
        if (r == R_FU) {
            float acc = 0.0f;
#pragma unroll
            for (int k = 0; k < 64; ++k)
                acc = fmaf(edges_tab[k] * 0.12f, edge_W[k * 64 + n], acc);
            NEWt[n] = lrelu(acc);
            return;
        }
        const float* src;
        const float* W;
        if (r < R_AGE)       { src = gender_tab + (size_t)r * 64;            W = user_W;            }
        else if (r < R_OCC)  { src = age_tab    + (size_t)(r - R_AGE) * 64;  W = user_W + 64 * 64;  }
        else if (r < R_AREA) { src = occ_tab    + (size_t)(r - R_OCC) * 64;  W = user_W + 128 * 64; }
        else if (r < R_RATE) { src = area_tab   + (size_t)(r - R_AREA) * 64; W = user_W + 192 * 64; }
        else                 { src = rate_tab   + (size_t)(r - R_RATE) * 64; W = item_W;            }
        float acc = 0.0f;
#pragma unroll
        for (int k = 0; k < 64; ++k)
            acc = fmaf(src[k], W[k * 64 + n], acc);
        Fu[(size_t)r * 64 + n] = acc;
        return;
    }

    // ---- B-table role: 64 padded cols, write fragment-ordered B2 ----
    const int g0 = (blk - NFUSEA) * 64;
    int ch = 0;
    while (g0 >= CUM[ch + 1]) ++ch;              // wave-uniform
    const int lo = LOG[ch], hi = HIG[ch], dl = DLT[ch];

    for (int rl = 0; rl < 16; ++rl) {
        int r = rl * 4 + rb;
        int g = g0 + r;
        float acc = 0.0f;
        if (g >= lo && g < hi) {
            int c = g + dl;                      // item column
            const float* src;
            const float* W;
            if (c < 26)        { src = genre_W    + (size_t)(c - 1) * 64;    W = item_W + 64 * 64;  }
            else if (c < 2212) { src = director_W + (size_t)(c - 26) * 64;   W = item_W + 128 * 64; }
            else               { src = actor_W    + (size_t)(c - 2212) * 64; W = item_W + 192 * 64; }
#pragma unroll
            for (int k = 0; k < 64; ++k)
                acc = fmaf(src[k], W[k * 64 + n], acc);
        }
        T[r * 65 + n] = acc;
    }
    __syncthreads();
    // pack to fragment-ordered B2: 16B slot index = kt*1024 + ks*256 + s*64 + q*16 + r16
    // thread (n2,sg) holds row n2, k-range [(g0&127)+sg*16, +16) within tile kt=g0>>7.
    int n2 = t >> 2, sg = t & 3;
    unsigned dw[8];
#pragma unroll
    for (int d = 0; d < 8; ++d)
        dw[d] = bf_rne_pair(T[(sg * 16 + 2 * d) * 65 + n2], T[(sg * 16 + 2 * d + 1) * 65 + n2]);
    const int kt = g0 >> 7;
    const int kl = (g0 & 127) + sg * 16;
    const int ks = kl >> 5;
    const int qa = (kl >> 3) & 3;                // 0 or 2; spans slots qa, qa+1
    const int s = n2 >> 4, r16b = n2 & 15;
    const size_t slot0 = (size_t)kt * 1024 + ks * 256 + s * 64 + qa * 16 + r16b;
    *(uint4*)(B2s + slot0 * 8)        = make_uint4(dw[0], dw[1], dw[2], dw[3]);
    *(uint4*)(B2s + (slot0 + 16) * 8) = make_uint4(dw[4], dw[5], dw[6], dw[7]);
}

// ---------------- K2: MFMA multi-hot GEMM from bitmask — no LDS, no barriers ----------------
// grid (64, NSLICE); block 256 = 4 waves; wave w -> m rows [16w,16w+16), all 64 n + count col.
__global__ __launch_bounds__(256) void k_item(const unsigned long long* __restrict__ M64,
                                              const short* __restrict__ B2s,
                                              float* __restrict__ P, float* __restrict__ C) {
    const int slc = blockIdx.y;
    const int kt0 = TS_[slc], kt1 = TS_[slc + 1];
    const int m0 = blockIdx.x * 64;
    const int t = threadIdx.x;
    const int lane = t & 63;
    const int w = __builtin_amdgcn_readfirstlane(t >> 6);
    const int q = lane >> 4, r16 = lane & 15;
    const int m = m0 + w * 16 + r16;

    f32x4 acc[5];
#pragma unroll
    for (int s = 0; s < 5; ++s) acc[s] = (f32x4){0.f, 0.f, 0.f, 0.f};

    const short o = (r16 == 0) ? (short)0x3f80 : (short)0;
    const bf16x8 ones = {o, o, o, o, o, o, o, o};

    const u32x4* mrow = (const u32x4*)(M64 + (size_t)m * (FB2COLS / 64)); // 16B per tile
    const bf16x8* b2 = (const bf16x8*)B2s;                                // 16B slots

    for (int kt = kt0; kt < kt1; ++kt) {
        u32x4 mv = mrow[kt];                       // bits for this row's 128-k tile
        const bf16x8* bp = b2 + (size_t)kt * 1024 + lane;
#pragma unroll
        for (int ks = 0; ks < 4; ++ks) {
            unsigned by = (mv[ks] >> (q * 8)) & 0xffu;
            u32x4 ev;
#pragma unroll
            for (int p2 = 0; p2 < 4; ++p2)
                ev[p2] = (((by >> (2 * p2)) & 1u) ? 0x3f80u : 0u)
                       | (((by >> (2 * p2 + 1)) & 1u) ? 0x3f800000u : 0u);
            bf16x8 a = __builtin_bit_cast(bf16x8, ev);
#pragma unroll
            for (int s = 0; s < 4; ++s) {
                bf16x8 b = bp[ks * 256 + s * 64];  // wave-contiguous 1KB, L2-hot
                acc[s] = __builtin_amdgcn_mfma_f32_16x16x32_bf16(a, b, acc[s], 0, 0, 0);
            }
            acc[4] = __builtin_amdgcn_mfma_f32_16x16x32_bf16(a, ones, acc[4], 0, 0, 0);
        }
    }
    // epilogue: D row = q*4+reg (within wave's 16), col = s*16+r16
    const size_t pb = (size_t)slc * BATCH + m0 + w * 16 + q * 4;
#pragma unroll
    for (int reg = 0; reg < 4; ++reg) {
        float* pr = P + (pb + reg) * 64 + r16;
        pr[0] = acc[0][reg];
        pr[16] = acc[1][reg];
        pr[32] = acc[2][reg];
        pr[48] = acc[3][reg];
    }
    if (r16 == 0) {
#pragma unroll
        for (int reg = 0; reg < 4; ++reg)
            C[(size_t)slc * BATCH + m0 + w * 16 + q * 4 + reg] = acc[4][reg];
    }
}

// ---------------- K3: finalize x,y, per-row dots, per-block s-partials ----------------
__device__ __forceinline__ float wred(float v) {
#pragma unroll
    for (int m = 1; m < 64; m <<= 1) v += __shfl_xor(v, m, 64);
    return v;
}

__global__ __launch_bounds__(256) void k_mid(const int* __restrict__ item, const int* __restrict__ edge_emb,
                                             const int* __restrict__ user_emb,
                                             const float* __restrict__ Fu, const float* __restrict__ user_b,
                                             const float* __restrict__ P, const float* __restrict__ C,
                                             const float* __restrict__ item_b, const float* __restrict__ edges_tab,
                                             const float* __restrict__ uu_w, const float* __restrict__ ui_w,
                                             const float* __restrict__ iu_w, const float* __restrict__ ii_w,
                                             float* __restrict__ X, float* __restrict__ Y,
                                             float* __restrict__ SC, float* __restrict__ SP) {
    const int t = threadIdx.x;
    const int n = t & 63;
    const int wv = __builtin_amdgcn_readfirstlane(t >> 6);
    const float uuw = uu_w[n], uiw = ui_w[n], iuw = iu_w[n], iiw = ii_w[n];
    const float ib = item_b[n], ub = user_b[n];
    const size_t cs = (size_t)BATCH * 64;
    float s1 = 0.0f, s2 = 0.0f, s3 = 0.0f, s4 = 0.0f;

    for (int i = 0; i < 4; ++i) {
        int b = blockIdx.x * 16 + wv * 4 + i;
        const int* ue = user_emb + (size_t)b * 4;
        float x = (Fu[(size_t)(R_GENDER + ue[0]) * 64 + n]
                 + Fu[(size_t)(R_AGE    + ue[1]) * 64 + n]
                 + Fu[(size_t)(R_OCC    + ue[2]) * 64 + n]
                 + Fu[(size_t)(R_AREA   + ue[3]) * 64 + n] + ub) * 0.12f;
        X[(size_t)b * 64 + n] = x;
        int ri = item[(size_t)b * ITEM_COLS];
        size_t base = (size_t)b * 64 + n;
        // slice groups: genre = {0}, director = {1,2,3}, actor = {4..14}
        float sg = P[base];
        float cg = C[b];
        float sd = 0.0f, cd = 0.0f, sa = 0.0f, ca = 0.0f;
#pragma unroll
        for (int s5 = 1; s5 < 4; ++s5) { sd += P[base + s5 * cs]; cd += C[s5 * BATCH + b]; }
#pragma unroll
        for (int s5 = 4; s5 < NSLICE; ++s5) { sa += P[base + s5 * cs]; ca += C[s5 * BATCH + b]; }
        float y = (Fu[(size_t)(R_RATE + ri) * 64 + n] + sg / cg + sd / cd + sa / ca + ib) * 0.12f;
        Y[(size_t)b * 64 + n] = y;
        float e = edges_tab[(size_t)edge_emb[b] * 64 + n] * 0.12f;
        float xe = x * e, ye = y * e;
        float r1 = wred(xe * uuw);  // x_xx
        float r2 = wred(xe * uiw);  // x_xy_x
        float r3 = wred(xe * iuw);  // y_yx_x
        float r4 = wred(ye * uiw);  // x_xy_y
        float r5 = wred(ye * iiw);  // y_yy
        float r6 = wred(ye * iuw);  // y_yx_y
        if (n == 0) {
            SC[b] = r1; SC[BATCH + b] = r2; SC[2 * BATCH + b] = r5; SC[3 * BATCH + b] = r6;
        }
        s1 = fmaf(r1, x, s1);
        s2 = fmaf(r4, y, s2);
        s3 = fmaf(r5, y, s3);
        s4 = fmaf(r3, x, s4);
    }
    __shared__ float sp[4][4][64];
    sp[wv][0][n] = s1; sp[wv][1][n] = s2; sp[wv][2][n] = s3; sp[wv][3][n] = s4;
    __syncthreads();
    int i2 = t >> 6;
    float v = sp[0][i2][n] + sp[1][i2][n] + sp[2][i2][n] + sp[3][i2][n];
    SP[(size_t)blockIdx.x * 256 + t] = v;
}

// ---------------- K4: final outputs (SP reduce + PB GEMM in-block) ----------------
__global__ __launch_bounds__(256) void k_out(const float* __restrict__ X, const float* __restrict__ Y,
                                             const float* __restrict__ SC, const float* __restrict__ SP,
                                             const float* __restrict__ NEWt, const float* __restrict__ edges_tab,
                                             const int* __restrict__ edge_emb,
                                             const float* __restrict__ uu_W1, const float* __restrict__ ui_W1,
                                             const float* __restrict__ iu_W1, const float* __restrict__ ii_W1,
                                             float* __restrict__ out) {
    const int t = threadIdx.x;
    const int i = t >> 6, n = t & 63;
    float s = 0.0f;
    for (int wb = 0; wb < 256; ++wb) s += SP[(size_t)wb * 256 + t];
    __shared__ float sl2[4][64];
    sl2[i][n] = s;
    __syncthreads();
    const float* W1 = (i == 0) ? uu_W1 : (i == 1) ? ui_W1 : (i == 2) ? ii_W1 : iu_W1;
    float p = 0.0f;
#pragma unroll
    for (int k = 0; k < 64; ++k) p = fmaf(sl2[i][k], W1[k * 64 + n], p);
    __shared__ float pbs[4][64];
    pbs[i][n] = p;
    __syncthreads();
    const float p1 = pbs[0][n], p2 = pbs[1][n], p3 = pbs[2][n], p4 = pbs[3][n];
    const float nw = NEWt[n];
#pragma unroll
    for (int j = 0; j < 8; ++j) {
        int b = blockIdx.x * 32 + j * 4 + i;
        float xx = SC[b], xyx = SC[BATCH + b], yy = SC[2 * BATCH + b], yxy = SC[3 * BATCH + b];
        float x = X[(size_t)b * 64 + n], y = Y[(size_t)b * 64 + n];
        float o1 = ((lrelu(xx * p1) + lrelu(xyx * p2)) * 0.5f + x) * 0.5f;
        float o2 = ((lrelu(yy * p3) + lrelu(yxy * p4)) * 0.5f + y) * 0.5f;
        float e = edges_tab[(size_t)edge_emb[b] * 64 + n] * 0.12f;
        float o3 = (nw + e) * 0.5f;
        out[(size_t)b * 64 + n] = o1;
        out[((size_t)BATCH + b) * 64 + n] = o2;
        out[((size_t)2 * BATCH + b) * 64 + n] = o3;
    }
}

// ---------------- launch ----------------
extern "C" void kernel_launch(void* const* d_in, const int* in_sizes, int n_in,
                              void* d_out, int out_size, void* d_ws, size_t ws_size,
                              hipStream_t stream) {
    (void)in_sizes; (void)n_in; (void)out_size; (void)ws_size;
    const int*   user_emb   = (const int*)  d_in[0];
    const int*   item_emb   = (const int*)  d_in[1];
    const int*   edge_emb   = (const int*)  d_in[2];
    const float* gender_tab = (const float*)d_in[3];
    const float* age_tab    = (const float*)d_in[4];
    const float* occ_tab    = (const float*)d_in[5];
    const float* area_tab   = (const float*)d_in[6];
    const float* user_W     = (const float*)d_in[7];
    const float* user_b     = (const float*)d_in[8];
    const float* rate_tab   = (const float*)d_in[9];
    const float* genre_W    = (const float*)d_in[10];
    const float* director_W = (const float*)d_in[11];
    const float* actor_W    = (const float*)d_in[12];
    const float* item_W     = (const float*)d_in[13];
    const float* item_b     = (const float*)d_in[14];
    const float* edges_tab  = (const float*)d_in[15];
    const float* uu_w       = (const float*)d_in[16];
    const float* ui_w       = (const float*)d_in[17];
    const float* iu_w       = (const float*)d_in[18];
    const float* ii_w       = (const float*)d_in[19];
    const float* edge_W     = (const float*)d_in[20];
    const float* uu_W1      = (const float*)d_in[21];
    const float* ui_W1      = (const float*)d_in[22];
    const float* iu_W1      = (const float*)d_in[23];
    const float* ii_W1      = (const float*)d_in[24];

    float* ws   = (float*)d_ws;
    float* Fu   = ws + OFF_FU;
    float* NEWt = ws + OFF_NEW;
    short* B2s  = (short*)(ws + OFF_FBT);
    unsigned long long* M64 = (unsigned long long*)(ws + OFF_MSK);
    float* X    = ws + OFF_X;
    float* Y    = ws + OFF_Y;
    float* P    = ws + OFF_P;
    float* C    = ws + OFF_C;
    float* SP   = ws + OFF_SP;
    float* SC   = ws + OFF_SC;
    float* out  = (float*)d_out;

    hipLaunchKernelGGL(k_fuse, dim3(NFUSEA + NFUSET + NPACK), dim3(256), 0, stream,
                       gender_tab, age_tab, occ_tab, area_tab, user_W, rate_tab,
                       item_W, edges_tab, edge_W, genre_W, director_W, actor_W,
                       item_emb, Fu, NEWt, B2s, M64);
    hipLaunchKernelGGL(k_item, dim3(BATCH / 64, NSLICE), dim3(256), 0, stream, M64, B2s, P, C);
    hipLaunchKernelGGL(k_mid, dim3(BATCH / 16), dim3(256), 0, stream,
                       item_emb, edge_emb, user_emb, Fu, user_b, P, C, item_b, edges_tab,
                       uu_w, ui_w, iu_w, ii_w, X, Y, SC, SP);
    hipLaunchKernelGGL(k_out, dim3(BATCH / 32), dim3(256), 0, stream,
                       X, Y, SC, SP, NEWt, edges_tab, edge_emb,
                       uu_W1, ui_W1, iu_W1, ii_W1, out);
}

// Round 4
// 337.178 us; speedup vs baseline: 1.1484x; 1.1484x over previous
//
#include <hip/hip_runtime.h>
#include <cstddef>

// ---------------- problem constants ----------------
constexpr int BATCH = 4096;
constexpr int ITEM_COLS = 10242;

// Fu row offsets (fp32 fused table: user fields + rate)
constexpr int R_GENDER = 0;      // 98 rows
constexpr int R_AGE    = 98;     // 7
constexpr int R_OCC    = 105;    // 21
constexpr int R_AREA   = 126;    // 3402
constexpr int R_RATE   = 3528;   // 6
constexpr int R_FU     = 3534;   // total Fu rows; row 3534 = NEW

// padded-col space: 9 chunks concatenated, each 128-aligned.
// padded col g (chunk ch) <-> item col c = g + DLT[ch]; valid iff LOG[ch] <= g < HIG[ch].
__device__ const int CUM[10] = {0, 128, 1280, 2432, 3840, 5248, 6656, 8064, 9472, 10880};
__device__ const int DLT[9]  = {0, -104, -168, -224, -296, -368, -432, -504, -576};
__device__ const int LOG[9]  = {1, 130, 1287, 2436, 3846, 5256, 6659, 8069, 9479};
__device__ const int HIG[9]  = {26, 1223, 2380, 3774, 5184, 6595, 7997, 9407, 10818};
constexpr int FB2COLS = 10880;          // 85 tiles of 128
constexpr int NTILE   = 85;
constexpr int NSLICE  = 15;             // group-aligned K-slices
// slice s covers tiles [TS_[s], TS_[s+1]); genre={tile 0}, director=tiles 1..18, actor=19..84
__device__ const int TS_[16] = {0, 1, 7, 13, 19, 25, 31, 37, 43, 49, 55, 61, 67, 73, 79, 85};

constexpr int NFUSEA = 884;             // 884*4 >= R_FU+1 rows
constexpr int NFUSET = FB2COLS / 64;    // 170 B-table blocks
constexpr int NPACK  = 1024;            // 1024*4 waves = 4096 rows

// pack metadata: per 64-bit mask word wq: validity mask + item-col base (compile-time)
struct PackTab { unsigned long long vm[NFUSET]; int c0[NFUSET]; };
constexpr PackTab make_packtab() {
    PackTab p{};
    const int CUMc[10] = {0, 128, 1280, 2432, 3840, 5248, 6656, 8064, 9472, 10880};
    const int DLTc[9]  = {0, -104, -168, -224, -296, -368, -432, -504, -576};
    const int LOGc[9]  = {1, 130, 1287, 2436, 3846, 5256, 6659, 8069, 9479};
    const int HIGc[9]  = {26, 1223, 2380, 3774, 5184, 6595, 7997, 9407, 10818};
    for (int wq = 0; wq < NFUSET; ++wq) {
        int g0 = wq * 64;
        int ch = 0;
        while (g0 >= CUMc[ch + 1]) ++ch;
        int lo = LOGc[ch] - g0; lo = lo < 0 ? 0 : lo;                  // in [0,63]
        int hi = HIGc[ch] - g0; hi = hi < 0 ? 0 : (hi > 64 ? 64 : hi); // in [0,64]
        unsigned long long hm = (hi >= 64) ? ~0ull : ((1ull << hi) - 1ull);
        unsigned long long lm = (lo <= 0) ? 0ull : ((1ull << lo) - 1ull);
        p.vm[wq] = hm & ~lm;
        p.c0[wq] = g0 + DLTc[ch];
    }
    return p;
}
__device__ constexpr PackTab PT = make_packtab();

// workspace layout (float slots)
constexpr size_t OFF_FU  = 0;                                    // 3534*64
constexpr size_t OFF_NEW = OFF_FU + (size_t)R_FU * 64;           // 64
constexpr size_t OFF_FBT = OFF_NEW + 64;                         // B2: 64*10880 bf16
constexpr size_t OFF_MSK = OFF_FBT + (size_t)64 * FB2COLS / 2;   // 4096*170 u64
constexpr size_t OFF_X   = OFF_MSK + (size_t)BATCH * (FB2COLS / 64) * 2;
constexpr size_t OFF_Y   = OFF_X + (size_t)BATCH * 64;
constexpr size_t OFF_P   = OFF_Y + (size_t)BATCH * 64;           // NSLICE*4096*64
constexpr size_t OFF_C   = OFF_P + (size_t)NSLICE * BATCH * 64;  // NSLICE*4096
constexpr size_t OFF_SP  = OFF_C + (size_t)NSLICE * BATCH;       // 256*256
constexpr size_t OFF_SC  = OFF_SP + 256ull * 256;                // 4*4096

typedef __attribute__((ext_vector_type(8))) short bf16x8;
typedef __attribute__((ext_vector_type(4))) float f32x4;
typedef __attribute__((ext_vector_type(4))) unsigned u32x4;

__device__ __forceinline__ float lrelu(float v) { return v >= 0.0f ? v : 0.01f * v; }

__device__ __forceinline__ unsigned bf_rne_pair(float lo, float hi) {
    unsigned ul = __builtin_bit_cast(unsigned, lo);
    unsigned uh = __builtin_bit_cast(unsigned, hi);
    ul += 0x7fffu + ((ul >> 16) & 1u);
    uh += 0x7fffu + ((uh >> 16) & 1u);
    return (ul >> 16) | (uh & 0xffff0000u);
}

// ---------------- K1: fused preprocessing ----------------
// blocks [0, NPACK): bit-pack item rows -> M64 (validity-masked). LONGEST ROLE FIRST.
// blocks [NPACK, NPACK+NFUSEA): Fu rows (4/block) + NEW row.
// blocks [NPACK+NFUSEA, +NFUSET): B2 table, MFMA-fragment-ordered bf16, pre-masked.
__global__ __launch_bounds__(256) void k_fuse(
        const float* __restrict__ gender_tab, const float* __restrict__ age_tab,
        const float* __restrict__ occ_tab, const float* __restrict__ area_tab,
        const float* __restrict__ user_W, const float* __restrict__ rate_tab,
        const float* __restrict__ item_W, const float* __restrict__ edges_tab,
        const float* __restrict__ edge_W, const float* __restrict__ genre_W,
        const float* __restrict__ director_W, const float* __restrict__ actor_W,
        const int* __restrict__ item,
        float* __restrict__ Fu, float* __restrict__ NEWt, short* __restrict__ B2s,
        unsigned long long* __restrict__ M64) {
    const int t = threadIdx.x;
    const int blk = blockIdx.x;

    if (blk < NPACK) {
        // ---- pack role: one wave per batch row; paired independent loads, deep MLP ----
        const int w = __builtin_amdgcn_readfirstlane(t >> 6);
        const int lane = t & 63;
        const int m = blk * 4 + w;
        const int* row = item + (size_t)m * ITEM_COLS;
        ulonglong2* dst = (ulonglong2*)(M64 + (size_t)m * (FB2COLS / 64));
#pragma unroll 5
        for (int pq = 0; pq < NFUSET / 2; ++pq) {
            int ca = PT.c0[2 * pq] + lane;                    // always in-bounds
            int cb = PT.c0[2 * pq + 1] + lane;
            cb = cb > ITEM_COLS - 1 ? ITEM_COLS - 1 : cb;     // global tail clamp
            int va = row[ca];
            int vb = row[cb];
            unsigned long long ba = __ballot(va != 0) & PT.vm[2 * pq];
            unsigned long long bb = __ballot(vb != 0) & PT.vm[2 * pq + 1];
            if (lane == 0) dst[pq] = (ulonglong2){ba, bb};
        }
        return;
    }

    const int n = t & 63;
    const int rb = __builtin_amdgcn_readfirstlane(t >> 6);
    __shared__ float T[64 * 65];

    if (blk < NPACK + NFUSEA) {
        int r = (blk - NPACK) * 4 + rb;
        if (r > R_FU) return;
        if (r == R_FU) {
            float acc = 0.0f;
#pragma unroll
            for (int k = 0; k < 64; ++k)
                acc = fmaf(edges_tab[k] * 0.12f, edge_W[k * 64 + n], acc);
            NEWt[n] = lrelu(acc);
            return;
        }
        const float* src;
        const float* W;
        if (r < R_AGE)       { src = gender_tab + (size_t)r * 64;            W = user_W;            }
        else if (r < R_OCC)  { src = age_tab    + (size_t)(r - R_AGE) * 64;  W = user_W + 64 * 64;  }
        else if (r < R_AREA) { src = occ_tab    + (size_t)(r - R_OCC) * 64;  W = user_W + 128 * 64; }
        else if (r < R_RATE) { src = area_tab   + (size_t)(r - R_AREA) * 64; W = user_W + 192 * 64; }
        else                 { src = rate_tab   + (size_t)(r - R_RATE) * 64; W = item_W;            }
        float acc = 0.0f;
#pragma unroll
        for (int k = 0; k < 64; ++k)
            acc = fmaf(src[k], W[k * 64 + n], acc);
        Fu[(size_t)r * 64 + n] = acc;
        return;
    }

    // ---- B-table role: 64 padded cols, write fragment-ordered B2 ----
    const int g0 = (blk - NPACK - NFUSEA) * 64;
    int ch = 0;
    while (g0 >= CUM[ch + 1]) ++ch;              // wave-uniform
    const int lo = LOG[ch], hi = HIG[ch], dl = DLT[ch];

    for (int rl = 0; rl < 16; ++rl) {
        int r = rl * 4 + rb;
        int g = g0 + r;
        float acc = 0.0f;
        if (g >= lo && g < hi) {
            int c = g + dl;                      // item column
            const float* src;
            const float* W;
            if (c < 26)        { src = genre_W    + (size_t)(c - 1) * 64;    W = item_W + 64 * 64;  }
            else if (c < 2212) { src = director_W + (size_t)(c - 26) * 64;   W = item_W + 128 * 64; }
            else               { src = actor_W    + (size_t)(c - 2212) * 64; W = item_W + 192 * 64; }
#pragma unroll
            for (int k = 0; k < 64; ++k)
                acc = fmaf(src[k], W[k * 64 + n], acc);
        }
        T[r * 65 + n] = acc;
    }
    __syncthreads();
    // pack to fragment-ordered B2: 16B slot index = kt*1024 + ks*256 + s*64 + q*16 + r16
    // thread (n2,sg) holds row n2, k-range [(g0&127)+sg*16, +16) within tile kt=g0>>7.
    int n2 = t >> 2, sg = t & 3;
    unsigned dw[8];
#pragma unroll
    for (int d = 0; d < 8; ++d)
        dw[d] = bf_rne_pair(T[(sg * 16 + 2 * d) * 65 + n2], T[(sg * 16 + 2 * d + 1) * 65 + n2]);
    const int kt = g0 >> 7;
    const int kl = (g0 & 127) + sg * 16;
    const int ks = kl >> 5;
    const int qa = (kl >> 3) & 3;                // 0 or 2; spans slots qa, qa+1
    const int s = n2 >> 4, r16b = n2 & 15;
    const size_t slot0 = (size_t)kt * 1024 + ks * 256 + s * 64 + qa * 16 + r16b;
    *(uint4*)(B2s + slot0 * 8)        = make_uint4(dw[0], dw[1], dw[2], dw[3]);
    *(uint4*)(B2s + (slot0 + 16) * 8) = make_uint4(dw[4], dw[5], dw[6], dw[7]);
}

// ---------------- K2: MFMA multi-hot GEMM from bitmask — no LDS, no barriers ----------------
// grid (64, NSLICE); block 256 = 4 waves; wave w -> m rows [16w,16w+16), all 64 n + count col.
__global__ __launch_bounds__(256) void k_item(const unsigned long long* __restrict__ M64,
                                              const short* __restrict__ B2s,
                                              float* __restrict__ P, float* __restrict__ C) {
    const int slc = blockIdx.y;
    const int kt0 = TS_[slc], kt1 = TS_[slc + 1];
    const int m0 = blockIdx.x * 64;
    const int t = threadIdx.x;
    const int lane = t & 63;
    const int w = __builtin_amdgcn_readfirstlane(t >> 6);
    const int q = lane >> 4, r16 = lane & 15;
    const int m = m0 + w * 16 + r16;

    f32x4 acc[5];
#pragma unroll
    for (int s = 0; s < 5; ++s) acc[s] = (f32x4){0.f, 0.f, 0.f, 0.f};

    const short o = (r16 == 0) ? (short)0x3f80 : (short)0;
    const bf16x8 ones = {o, o, o, o, o, o, o, o};

    const u32x4* mrow = (const u32x4*)(M64 + (size_t)m * (FB2COLS / 64)); // 16B per tile
    const bf16x8* b2 = (const bf16x8*)B2s;                                // 16B slots

    for (int kt = kt0; kt < kt1; ++kt) {
        u32x4 mv = mrow[kt];                       // bits for this row's 128-k tile
        const bf16x8* bp = b2 + (size_t)kt * 1024 + lane;
#pragma unroll
        for (int ks = 0; ks < 4; ++ks) {
            unsigned by = (mv[ks] >> (q * 8)) & 0xffu;
            u32x4 ev;
#pragma unroll
            for (int p2 = 0; p2 < 4; ++p2)
                ev[p2] = (((by >> (2 * p2)) & 1u) ? 0x3f80u : 0u)
                       | (((by >> (2 * p2 + 1)) & 1u) ? 0x3f800000u : 0u);
            bf16x8 a = __builtin_bit_cast(bf16x8, ev);
#pragma unroll
            for (int s = 0; s < 4; ++s) {
                bf16x8 b = bp[ks * 256 + s * 64];  // wave-contiguous 1KB, L2-hot
                acc[s] = __builtin_amdgcn_mfma_f32_16x16x32_bf16(a, b, acc[s], 0, 0, 0);
            }
            acc[4] = __builtin_amdgcn_mfma_f32_16x16x32_bf16(a, ones, acc[4], 0, 0, 0);
        }
    }
    // epilogue: D row = q*4+reg (within wave's 16), col = s*16+r16
    const size_t pb = (size_t)slc * BATCH + m0 + w * 16 + q * 4;
#pragma unroll
    for (int reg = 0; reg < 4; ++reg) {
        float* pr = P + (pb + reg) * 64 + r16;
        pr[0] = acc[0][reg];
        pr[16] = acc[1][reg];
        pr[32] = acc[2][reg];
        pr[48] = acc[3][reg];
    }
    if (r16 == 0) {
#pragma unroll
        for (int reg = 0; reg < 4; ++reg)
            C[(size_t)slc * BATCH + m0 + w * 16 + q * 4 + reg] = acc[4][reg];
    }
}

// ---------------- K3: finalize x,y, per-row dots, per-block s-partials ----------------
__device__ __forceinline__ float wred(float v) {
#pragma unroll
    for (int m = 1; m < 64; m <<= 1) v += __shfl_xor(v, m, 64);
    return v;
}

__global__ __launch_bounds__(256) void k_mid(const int* __restrict__ item, const int* __restrict__ edge_emb,
                                             const int* __restrict__ user_emb,
                                             const float* __restrict__ Fu, const float* __restrict__ user_b,
                                             const float* __restrict__ P, const float* __restrict__ C,
                                             const float* __restrict__ item_b, const float* __restrict__ edges_tab,
                                             const float* __restrict__ uu_w, const float* __restrict__ ui_w,
                                             const float* __restrict__ iu_w, const float* __restrict__ ii_w,
                                             float* __restrict__ X, float* __restrict__ Y,
                                             float* __restrict__ SC, float* __restrict__ SP) {
    const int t = threadIdx.x;
    const int n = t & 63;
    const int wv = __builtin_amdgcn_readfirstlane(t >> 6);
    const float uuw = uu_w[n], uiw = ui_w[n], iuw = iu_w[n], iiw = ii_w[n];
    const float ib = item_b[n], ub = user_b[n];
    const size_t cs = (size_t)BATCH * 64;
    float s1 = 0.0f, s2 = 0.0f, s3 = 0.0f, s4 = 0.0f;

    for (int i = 0; i < 4; ++i) {
        int b = blockIdx.x * 16 + wv * 4 + i;
        const int* ue = user_emb + (size_t)b * 4;
        float x = (Fu[(size_t)(R_GENDER + ue[0]) * 64 + n]
                 + Fu[(size_t)(R_AGE    + ue[1]) * 64 + n]
                 + Fu[(size_t)(R_OCC    + ue[2]) * 64 + n]
                 + Fu[(size_t)(R_AREA   + ue[3]) * 64 + n] + ub) * 0.12f;
        X[(size_t)b * 64 + n] = x;
        int ri = item[(size_t)b * ITEM_COLS];
        size_t base = (size_t)b * 64 + n;
        // slice groups: genre = {0}, director = {1,2,3}, actor = {4..14}
        float sg = P[base];
        float cg = C[b];
        float sd = 0.0f, cd = 0.0f, sa = 0.0f, ca = 0.0f;
#pragma unroll
        for (int s5 = 1; s5 < 4; ++s5) { sd += P[base + s5 * cs]; cd += C[s5 * BATCH + b]; }
#pragma unroll
        for (int s5 = 4; s5 < NSLICE; ++s5) { sa += P[base + s5 * cs]; ca += C[s5 * BATCH + b]; }
        float y = (Fu[(size_t)(R_RATE + ri) * 64 + n] + sg / cg + sd / cd + sa / ca + ib) * 0.12f;
        Y[(size_t)b * 64 + n] = y;
        float e = edges_tab[(size_t)edge_emb[b] * 64 + n] * 0.12f;
        float xe = x * e, ye = y * e;
        float r1 = wred(xe * uuw);  // x_xx
        float r2 = wred(xe * uiw);  // x_xy_x
        float r3 = wred(xe * iuw);  // y_yx_x
        float r4 = wred(ye * uiw);  // x_xy_y
        float r5 = wred(ye * iiw);  // y_yy
        float r6 = wred(ye * iuw);  // y_yx_y
        if (n == 0) {
            SC[b] = r1; SC[BATCH + b] = r2; SC[2 * BATCH + b] = r5; SC[3 * BATCH + b] = r6;
        }
        s1 = fmaf(r1, x, s1);
        s2 = fmaf(r4, y, s2);
        s3 = fmaf(r5, y, s3);
        s4 = fmaf(r3, x, s4);
    }
    __shared__ float sp[4][4][64];
    sp[wv][0][n] = s1; sp[wv][1][n] = s2; sp[wv][2][n] = s3; sp[wv][3][n] = s4;
    __syncthreads();
    int i2 = t >> 6;
    float v = sp[0][i2][n] + sp[1][i2][n] + sp[2][i2][n] + sp[3][i2][n];
    SP[(size_t)blockIdx.x * 256 + t] = v;
}

// ---------------- K4: final outputs (SP reduce + PB GEMM in-block) ----------------
__global__ __launch_bounds__(256) void k_out(const float* __restrict__ X, const float* __restrict__ Y,
                                             const float* __restrict__ SC, const float* __restrict__ SP,
                                             const float* __restrict__ NEWt, const float* __restrict__ edges_tab,
                                             const int* __restrict__ edge_emb,
                                             const float* __restrict__ uu_W1, const float* __restrict__ ui_W1,
                                             const float* __restrict__ iu_W1, const float* __restrict__ ii_W1,
                                             float* __restrict__ out) {
    const int t = threadIdx.x;
    const int i = t >> 6, n = t & 63;
    float s = 0.0f;
    for (int wb = 0; wb < 256; ++wb) s += SP[(size_t)wb * 256 + t];
    __shared__ float sl2[4][64];
    sl2[i][n] = s;
    __syncthreads();
    const float* W1 = (i == 0) ? uu_W1 : (i == 1) ? ui_W1 : (i == 2) ? ii_W1 : iu_W1;
    float p = 0.0f;
#pragma unroll
    for (int k = 0; k < 64; ++k) p = fmaf(sl2[i][k], W1[k * 64 + n], p);
    __shared__ float pbs[4][64];
    pbs[i][n] = p;
    __syncthreads();
    const float p1 = pbs[0][n], p2 = pbs[1][n], p3 = pbs[2][n], p4 = pbs[3][n];
    const float nw = NEWt[n];
#pragma unroll
    for (int j = 0; j < 8; ++j) {
        int b = blockIdx.x * 32 + j * 4 + i;
        float xx = SC[b], xyx = SC[BATCH + b], yy = SC[2 * BATCH + b], yxy = SC[3 * BATCH + b];
        float x = X[(size_t)b * 64 + n], y = Y[(size_t)b * 64 + n];
        float o1 = ((lrelu(xx * p1) + lrelu(xyx * p2)) * 0.5f + x) * 0.5f;
        float o2 = ((lrelu(yy * p3) + lrelu(yxy * p4)) * 0.5f + y) * 0.5f;
        float e = edges_tab[(size_t)edge_emb[b] * 64 + n] * 0.12f;
        float o3 = (nw + e) * 0.5f;
        out[(size_t)b * 64 + n] = o1;
        out[((size_t)BATCH + b) * 64 + n] = o2;
        out[((size_t)2 * BATCH + b) * 64 + n] = o3;
    }
}

// ---------------- launch ----------------
extern "C" void kernel_launch(void* const* d_in, const int* in_sizes, int n_in,
                              void* d_out, int out_size, void* d_ws, size_t ws_size,
                              hipStream_t stream) {
    (void)in_sizes; (void)n_in; (void)out_size; (void)ws_size;
    const int*   user_emb   = (const int*)  d_in[0];
    const int*   item_emb   = (const int*)  d_in[1];
    const int*   edge_emb   = (const int*)  d_in[2];
    const float* gender_tab = (const float*)d_in[3];
    const float* age_tab    = (const float*)d_in[4];
    const float* occ_tab    = (const float*)d_in[5];
    const float* area_tab   = (const float*)d_in[6];
    const float* user_W     = (const float*)d_in[7];
    const float* user_b     = (const float*)d_in[8];
    const float* rate_tab   = (const float*)d_in[9];
    const float* genre_W    = (const float*)d_in[10];
    const float* director_W = (const float*)d_in[11];
    const float* actor_W    = (const float*)d_in[12];
    const float* item_W     = (const float*)d_in[13];
    const float* item_b     = (const float*)d_in[14];
    const float* edges_tab  = (const float*)d_in[15];
    const float* uu_w       = (const float*)d_in[16];
    const float* ui_w       = (const float*)d_in[17];
    const float* iu_w       = (const float*)d_in[18];
    const float* ii_w       = (const float*)d_in[19];
    const float* edge_W     = (const float*)d_in[20];
    const float* uu_W1      = (const float*)d_in[21];
    const float* ui_W1      = (const float*)d_in[22];
    const float* iu_W1      = (const float*)d_in[23];
    const float* ii_W1      = (const float*)d_in[24];

    float* ws   = (float*)d_ws;
    float* Fu   = ws + OFF_FU;
    float* NEWt = ws + OFF_NEW;
    short* B2s  = (short*)(ws + OFF_FBT);
    unsigned long long* M64 = (unsigned long long*)(ws + OFF_MSK);
    float* X    = ws + OFF_X;
    float* Y    = ws + OFF_Y;
    float* P    = ws + OFF_P;
    float* C    = ws + OFF_C;
    float* SP   = ws + OFF_SP;
    float* SC   = ws + OFF_SC;
    float* out  = (float*)d_out;

    hipLaunchKernelGGL(k_fuse, dim3(NPACK + NFUSEA + NFUSET), dim3(256), 0, stream,
                       gender_tab, age_tab, occ_tab, area_tab, user_W, rate_tab,
                       item_W, edges_tab, edge_W, genre_W, director_W, actor_W,
                       item_emb, Fu, NEWt, B2s, M64);
    hipLaunchKernelGGL(k_item, dim3(BATCH / 64, NSLICE), dim3(256), 0, stream, M64, B2s, P, C);
    hipLaunchKernelGGL(k_mid, dim3(BATCH / 16), dim3(256), 0, stream,
                       item_emb, edge_emb, user_emb, Fu, user_b, P, C, item_b, edges_tab,
                       uu_w, ui_w, iu_w, ii_w, X, Y, SC, SP);
    hipLaunchKernelGGL(k_out, dim3(BATCH / 32), dim3(256), 0, stream,
                       X, Y, SC, SP, NEWt, edges_tab, edge_emb,
                       uu_W1, ui_W1, iu_W1, ii_W1, out);
}